// Round 1
// baseline (64.476 us; speedup 1.0000x reference)
//
#include <hip/hip_runtime.h>

// LIF spike recurrence over time axis.
// x: [B=32, T=10, C=128, H=32, W=32] fp32 -> spikes same shape fp32.
// mem_t = tau*mem_{t-1} + x_t; spike = (mem_t > thresh); mem_t *= (1-spike).
// Each thread owns 4 consecutive inner elements (float4), loops over T in
// registers. Fully coalesced: inner dim C*H*W = 131072 floats contiguous.

#define LIF_T 10
#define LIF_INNER4 32768   // C*H*W/4 = 128*32*32/4
#define LIF_TAU 0.5f
#define LIF_THRESH 1.0f

__global__ void __launch_bounds__(256) lif_kernel(const float4* __restrict__ x,
                                                  float4* __restrict__ y) {
    const int i = blockIdx.x * blockDim.x + threadIdx.x;   // 0 .. INNER4-1
    const int b = blockIdx.y;                               // batch
    const size_t base = (size_t)b * LIF_T * LIF_INNER4 + i;

    float4 mem = make_float4(0.f, 0.f, 0.f, 0.f);

#pragma unroll
    for (int t = 0; t < LIF_T; ++t) {
        const size_t idx = base + (size_t)t * LIF_INNER4;
        float4 xv = x[idx];

        mem.x = mem.x * LIF_TAU + xv.x;
        mem.y = mem.y * LIF_TAU + xv.y;
        mem.z = mem.z * LIF_TAU + xv.z;
        mem.w = mem.w * LIF_TAU + xv.w;

        float4 sp;
        sp.x = (mem.x - LIF_THRESH > 0.f) ? 1.f : 0.f;
        sp.y = (mem.y - LIF_THRESH > 0.f) ? 1.f : 0.f;
        sp.z = (mem.z - LIF_THRESH > 0.f) ? 1.f : 0.f;
        sp.w = (mem.w - LIF_THRESH > 0.f) ? 1.f : 0.f;

        y[idx] = sp;

        // hard reset: mem <- (1 - spike) * mem
        mem.x = (sp.x > 0.f) ? 0.f : mem.x;
        mem.y = (sp.y > 0.f) ? 0.f : mem.y;
        mem.z = (sp.z > 0.f) ? 0.f : mem.z;
        mem.w = (sp.w > 0.f) ? 0.f : mem.w;
    }
}

extern "C" void kernel_launch(void* const* d_in, const int* in_sizes, int n_in,
                              void* d_out, int out_size, void* d_ws, size_t ws_size,
                              hipStream_t stream) {
    const float4* x = (const float4*)d_in[0];
    float4* y = (float4*)d_out;

    dim3 block(256, 1, 1);
    dim3 grid(LIF_INNER4 / 256, 32, 1);   // 128 blocks x 32 batches = 4096 blocks
    lif_kernel<<<grid, block, 0, stream>>>(x, y);
}

// Round 3
// 60.119 us; speedup vs baseline: 1.0725x; 1.0725x over previous
//
#include <hip/hip_runtime.h>

// LIF spike recurrence over time axis.
// x: [B=32, T=10, C=128, H=32, W=32] fp32 -> spikes same shape fp32.
// mem_t = tau*mem_{t-1} + x_t; spike = (mem_t > thresh); mem_t *= (1-spike).
//
// R3: same as R2 but using native clang ext_vector float4 so the
// nontemporal builtins accept the pointer (HIP_vector_type is a struct,
// rejected by __builtin_nontemporal_*).
//   - nontemporal load/store: pure 335MB stream, no reuse -> nt cache bits
//   - 2 independent columns/thread: 2x outstanding loads, 2 indep chains

typedef float f32x4 __attribute__((ext_vector_type(4)));

#define LIF_T 10
#define LIF_INNER4 32768       // C*H*W/4 per (b,t) slab
#define LIF_HALF 16384         // columns handled at offset 0 and +HALF
#define LIF_TAU 0.5f
#define LIF_THRESH 1.0f

__global__ void __launch_bounds__(256) lif_kernel(const f32x4* __restrict__ x,
                                                  f32x4* __restrict__ y) {
    const int i = blockIdx.x * blockDim.x + threadIdx.x;   // 0 .. HALF-1
    const int b = blockIdx.y;
    const size_t base0 = (size_t)b * LIF_T * LIF_INNER4 + i;
    const size_t base1 = base0 + LIF_HALF;

    f32x4 m0 = (f32x4)(0.f);
    f32x4 m1 = (f32x4)(0.f);

#pragma unroll
    for (int t = 0; t < LIF_T; ++t) {
        const size_t i0 = base0 + (size_t)t * LIF_INNER4;
        const size_t i1 = base1 + (size_t)t * LIF_INNER4;
        f32x4 x0 = __builtin_nontemporal_load(&x[i0]);
        f32x4 x1 = __builtin_nontemporal_load(&x[i1]);

        m0 = m0 * LIF_TAU + x0;
        m1 = m1 * LIF_TAU + x1;

        f32x4 s0, s1;
        s0.x = (m0.x > LIF_THRESH) ? 1.f : 0.f;
        s0.y = (m0.y > LIF_THRESH) ? 1.f : 0.f;
        s0.z = (m0.z > LIF_THRESH) ? 1.f : 0.f;
        s0.w = (m0.w > LIF_THRESH) ? 1.f : 0.f;
        s1.x = (m1.x > LIF_THRESH) ? 1.f : 0.f;
        s1.y = (m1.y > LIF_THRESH) ? 1.f : 0.f;
        s1.z = (m1.z > LIF_THRESH) ? 1.f : 0.f;
        s1.w = (m1.w > LIF_THRESH) ? 1.f : 0.f;

        __builtin_nontemporal_store(s0, &y[i0]);
        __builtin_nontemporal_store(s1, &y[i1]);

        // hard reset: mem <- (1 - spike) * mem
        m0.x = (s0.x > 0.f) ? 0.f : m0.x;
        m0.y = (s0.y > 0.f) ? 0.f : m0.y;
        m0.z = (s0.z > 0.f) ? 0.f : m0.z;
        m0.w = (s0.w > 0.f) ? 0.f : m0.w;
        m1.x = (s1.x > 0.f) ? 0.f : m1.x;
        m1.y = (s1.y > 0.f) ? 0.f : m1.y;
        m1.z = (s1.z > 0.f) ? 0.f : m1.z;
        m1.w = (s1.w > 0.f) ? 0.f : m1.w;
    }
}

extern "C" void kernel_launch(void* const* d_in, const int* in_sizes, int n_in,
                              void* d_out, int out_size, void* d_ws, size_t ws_size,
                              hipStream_t stream) {
    const f32x4* x = (const f32x4*)d_in[0];
    f32x4* y = (f32x4*)d_out;

    dim3 block(256, 1, 1);
    dim3 grid(LIF_HALF / 256, 32, 1);   // 64 x 32 = 2048 blocks
    lif_kernel<<<grid, block, 0, stream>>>(x, y);
}